// Round 4
// baseline (1773.432 us; speedup 1.0000x reference)
//
#include <hip/hip_runtime.h>
#include <hip/hip_fp16.h>
#include <math.h>

// GraphCast mesh2grid decoder: emb MLP -> edge MLP (+gathers, residual) ->
// scatter-sum (standalone agg kernel) -> node MLP (+residual).
// All GEMMs in f16 MFMA, fp32 accum.  K-loop is reg-double-buffered with
// explicit ping-pong (no copy movs); global->reg prefetch loads are not
// drained by __syncthreads, so slab s+1 flies under slab s's MFMAs.

#define NG 65536
#define NM 40962
#define NE 196608

using f16   = _Float16;
using f16x8 = __attribute__((ext_vector_type(8))) _Float16;
using f16x4 = __attribute__((ext_vector_type(4))) _Float16;
using f32x4 = __attribute__((ext_vector_type(4))) float;

// ---------------------------------------------------------------- prep kernels

__global__ void cvt_rows_kernel(const float* __restrict__ in, f16* __restrict__ out, int n4) {
    int stride = gridDim.x * blockDim.x;
    for (int i = blockIdx.x * blockDim.x + threadIdx.x; i < n4; i += stride) {
        float4 v = ((const float4*)in)[i];
        f16x4 o; o[0] = (f16)v.x; o[1] = (f16)v.y; o[2] = (f16)v.z; o[3] = (f16)v.w;
        ((f16x4*)out)[i] = o;
    }
}

// W [K][512] f32  ->  WT [512][K] f16   (writes coalesced along k)
__global__ void transpose_w_kernel(const float* __restrict__ W, f16* __restrict__ WT, int K) {
    int total = K * 512;
    int stride = gridDim.x * blockDim.x;
    for (int idx = blockIdx.x * blockDim.x + threadIdx.x; idx < total; idx += stride) {
        int k = idx % K;
        int c = idx / K;
        WT[idx] = (f16)W[(size_t)k * 512 + c];
    }
}

// ---------------------------------------------------------------- CSR build

__global__ void count_kernel(const int* __restrict__ dst, int* __restrict__ counts) {
    int i = blockIdx.x * 256 + threadIdx.x;
    if (i < NE) atomicAdd(&counts[dst[i]], 1);
}

__global__ void scan_kernel(const int* __restrict__ counts, int* __restrict__ offs,
                            int* __restrict__ cursor) {
    __shared__ int part[1024];
    int t = threadIdx.x;
    int base = t * 64;
    int loc[64];
    int s = 0;
    #pragma unroll
    for (int i = 0; i < 64; ++i) { loc[i] = s; s += counts[base + i]; }
    part[t] = s;
    __syncthreads();
    for (int off = 1; off < 1024; off <<= 1) {
        int v = (t >= off) ? part[t - off] : 0;
        __syncthreads();
        part[t] += v;
        __syncthreads();
    }
    int pre = (t == 0) ? 0 : part[t - 1];
    #pragma unroll
    for (int i = 0; i < 64; ++i) { int o = pre + loc[i]; offs[base + i] = o; cursor[base + i] = o; }
    if (t == 1023) offs[65536] = pre + s;   // == NE
}

__global__ void fill_kernel(const int* __restrict__ dst, int* __restrict__ cursor,
                            int* __restrict__ perm) {
    int i = blockIdx.x * 256 + threadIdx.x;
    if (i < NE) {
        int d = dst[i];
        int p = atomicAdd(&cursor[d], 1);
        perm[p] = i;
    }
}

// ---------------------------------------------------------------- agg kernel
// agg[node] = sum over incident edges of e_new[edge]  (CSR order).
// One wave per node, 4 waves/block, high occupancy -> TLP hides gather latency.

__global__ void agg_kernel(const f16* __restrict__ enew,
                           const int* __restrict__ offs,
                           const int* __restrict__ perm,
                           f16* __restrict__ agg) {
    int node = blockIdx.x * 4 + (threadIdx.x >> 6);
    int lane = threadIdx.x & 63;
    int beg = offs[node], end = offs[node + 1];
    float a[8] = {0.f, 0.f, 0.f, 0.f, 0.f, 0.f, 0.f, 0.f};
    for (int j = beg; j < end; ++j) {
        int e = perm[j];
        f16x8 v = *(const f16x8*)(enew + (size_t)e * 512 + lane * 8);
        #pragma unroll
        for (int i = 0; i < 8; ++i) a[i] += (float)v[i];
    }
    f16x8 o;
    #pragma unroll
    for (int i = 0; i < 8; ++i) o[i] = (f16)a[i];
    *(f16x8*)(agg + (size_t)node * 512 + lane * 8) = o;
}

// ---------------------------------------------------------------- fused MLP
// MODE 0: emb   x=[E,4]     stage-1 fp32 direct      out: e_f16
// MODE 1: edge  A=concat(e, mesh[src], grid[dst])    K1=1536, out: enew_f16 (+e resid)
// MODE 2: node  A=concat(grid, agg)  (agg in meshA)  K1=1024, out: d_out f32 (+grid resid)
//
// 64 rows/block, 512 threads (8 waves).  Wave w owns output cols [w*64, w*64+64).
// Stage1 -> SiLU -> h in LDS (f16, XOR-swizzled 16B chunks) -> Stage2 -> LN -> store.

template <int MODE>
__global__ __launch_bounds__(512, 2) __attribute__((flatten))
void mlp_fused(const float* __restrict__ xin,
               const f16*  eA,                      // aliases outF16 in MODE 1: no restrict
               const f16*  __restrict__ meshA,      // MODE 2: agg rows
               const f16*  __restrict__ gridA,
               const int*  __restrict__ srcIdx,
               const int*  __restrict__ dstIdx,
               const float* __restrict__ W0emb,
               const f16*  __restrict__ W0T,
               const float* __restrict__ b0,
               const f16*  __restrict__ W1T,
               const float* __restrict__ b1,
               const float* __restrict__ gma,
               const float* __restrict__ bta,
               const float* __restrict__ resF32,
               float* __restrict__ outF32,
               f16*  outF16)                        // aliases eA in MODE 1: no restrict
{
    constexpr int K1  = (MODE == 1) ? 1536 : (MODE == 2 ? 1024 : 64);
    constexpr int NS1 = (MODE == 0) ? 0 : K1 / 64;

    __shared__ __align__(16) f16 hbuf[64 * 512];    // h tile
    __shared__ __align__(16) f16 btile[512 * 64];   // B k-slab: [col][64k]
    __shared__ __align__(16) f16 atile[64 * 64];    // A k-slab: [row][64k]
    __shared__ float red1[64][8];
    __shared__ float red2[64][8];
    __shared__ float mrow[64];
    __shared__ float rrow[64];
    __shared__ float xemb[256];

    const int tid  = threadIdx.x;
    const int lane = tid & 63;
    const int w    = tid >> 6;
    const int l15  = lane & 15;
    const int lg   = lane >> 4;
    const int row0 = blockIdx.x * 64;

    // staging decomposition: each thread owns one 16B chunk per slab round
    const int ar   = tid >> 3;      // row/col-in-slab 0..63 (plus q*64 for B)
    const int ap   = tid & 7;       // chunk position 0..7
    const int aswz = ap ^ (ar & 7); // swizzled chunk slot

    int rid = 0, sid = 0, did = 0;
    if constexpr (MODE == 1 || MODE == 2) rid = row0 + ar;
    if constexpr (MODE == 1) { sid = srcIdx[rid]; did = dstIdx[rid]; }

    // B k-slab loader (stage-1 or stage-2 weights)
    auto ldB = [&](const f16* WT, int K, int s, f16x8 (&b_)[8]) {
        const int k0 = s * 64;
        #pragma unroll
        for (int q = 0; q < 8; ++q)
            b_[q] = *(const f16x8*)(WT + (size_t)(q * 64 + ar) * K + (k0 + ap * 8));
    };
    // A k-slab loader (stage-1 gathered/contiguous rows)
    auto ldA1 = [&](int s, f16x8& a_) {
        const int k0 = s * 64;
        if constexpr (MODE == 1) {
            const f16* p;
            if (k0 < 512)       p = eA    + (size_t)rid * 512 + (k0 + ap * 8);
            else if (k0 < 1024) p = meshA + (size_t)sid * 512 + (k0 - 512 + ap * 8);
            else                p = gridA + (size_t)did * 512 + (k0 - 1024 + ap * 8);
            a_ = *(const f16x8*)p;
        } else if constexpr (MODE == 2) {
            const f16* p = (k0 < 512)
                ? (gridA + (size_t)rid * 512 + (k0 + ap * 8))
                : (meshA + (size_t)rid * 512 + (k0 - 512 + ap * 8));   // agg rows
            a_ = *(const f16x8*)p;
        }
    };

    f16x8 cvA[8], cvB[8];                // stage-2 B ping-pong regs
    if constexpr (MODE == 0) ldB(W1T, 512, 0, cvA);  // prefetch stage-2 slab 0 early

    f16x8 avA, avB, bvA[8], bvB[8];      // stage-1 ping-pong regs
    if constexpr (MODE == 1 || MODE == 2) { ldA1(0, avA); ldB(W0T, K1, 0, bvA); }

    // ---- MODE 0 stage-1: [64,4] @ [4,512] + SiLU, fp32 direct ----
    if constexpr (MODE == 0) {
        if (tid < 256) xemb[tid] = xin[(size_t)row0 * 4 + tid];
        __syncthreads();
        const int c = tid;
        float w0c0 = W0emb[c], w0c1 = W0emb[512 + c], w0c2 = W0emb[1024 + c], w0c3 = W0emb[1536 + c];
        float b0c = b0[c];
        const int cs = c >> 3, c7 = c & 7;
        #pragma unroll 4
        for (int r = 0; r < 64; ++r) {
            float v = b0c;
            v = fmaf(xemb[r * 4 + 0], w0c0, v);
            v = fmaf(xemb[r * 4 + 1], w0c1, v);
            v = fmaf(xemb[r * 4 + 2], w0c2, v);
            v = fmaf(xemb[r * 4 + 3], w0c3, v);
            v = v / (1.f + __expf(-v));                       // SiLU
            hbuf[r * 512 + ((cs ^ (r & 7)) * 8) + c7] = (f16)v;
        }
    }

    // ---- stage-1 MFMA GEMM (MODE 1/2): acc[64,512] = A[64,K1] @ W0T^T ----
    f32x4 acc2[4][4] = {};               // stage-2 accumulator (declared early; zero-init)
    if constexpr (MODE == 1 || MODE == 2) {
        f32x4 acc[4][4] = {};

        auto step1 = [&](int s, f16x8& aC, f16x8 (&bC)[8], f16x8& aN, f16x8 (&bN)[8]) {
            __syncthreads();   // previous step's compute done reading slabs
            *(f16x8*)&atile[ar * 64 + aswz * 8] = aC;
            #pragma unroll
            for (int q = 0; q < 8; ++q)
                *(f16x8*)&btile[(q * 64 + ar) * 64 + aswz * 8] = bC[q];
            __syncthreads();

            // prefetch next slab: latency hides under this step's MFMAs
            if (s + 1 < NS1) { ldA1(s + 1, aN); ldB(W0T, K1, s + 1, bN); }

            #pragma unroll
            for (int ks = 0; ks < 2; ++ks) {
                const int ch = ks * 4 + lg;
                f16x8 af[4];
                #pragma unroll
                for (int rf = 0; rf < 4; ++rf) {
                    int r = rf * 16 + l15;
                    af[rf] = *(const f16x8*)&atile[r * 64 + ((ch ^ (r & 7)) * 8)];
                }
                #pragma unroll
                for (int cf = 0; cf < 4; ++cf) {
                    int c = w * 64 + cf * 16 + l15;
                    f16x8 bf = *(const f16x8*)&btile[c * 64 + ((ch ^ (c & 7)) * 8)];
                    #pragma unroll
                    for (int rf = 0; rf < 4; ++rf)
                        acc[rf][cf] = __builtin_amdgcn_mfma_f32_16x16x32_f16(af[rf], bf, acc[rf][cf], 0, 0, 0);
                }
            }
        };

        #pragma unroll 1
        for (int s = 0; s < NS1; s += 2) {
            step1(s,     avA, bvA, avB, bvB);
            step1(s + 1, avB, bvB, avA, bvA);
        }

        // prefetch stage-2 slab 0 (flies during the h epilogue below)
        ldB(W1T, 512, 0, cvA);

        // h = silu(acc + b0) -> hbuf
        float b0c[4];
        #pragma unroll
        for (int cf = 0; cf < 4; ++cf) b0c[cf] = b0[w * 64 + cf * 16 + l15];
        #pragma unroll
        for (int rf = 0; rf < 4; ++rf)
            #pragma unroll
            for (int i = 0; i < 4; ++i) {
                int r = rf * 16 + lg * 4 + i;
                #pragma unroll
                for (int cf = 0; cf < 4; ++cf) {
                    int c = w * 64 + cf * 16 + l15;
                    float v = acc[rf][cf][i] + b0c[cf];
                    v = v / (1.f + __expf(-v));
                    hbuf[r * 512 + (((c >> 3) ^ (r & 7)) * 8) + (c & 7)] = (f16)v;
                }
            }
    }

    // ---- stage-2 MFMA GEMM: acc2[64,512] = h[64,512] @ W1T^T ----
    {
        auto step2 = [&](int s, f16x8 (&cC)[8], f16x8 (&cN)[8]) {
            __syncthreads();   // h-writes visible / btile free
            #pragma unroll
            for (int q = 0; q < 8; ++q)
                *(f16x8*)&btile[(q * 64 + ar) * 64 + aswz * 8] = cC[q];
            __syncthreads();

            if (s < 7) ldB(W1T, 512, s + 1, cN);

            #pragma unroll
            for (int ks = 0; ks < 2; ++ks) {
                const int chb = s * 8 + ks * 4 + lg;
                const int ch  = ks * 4 + lg;
                f16x8 af[4];
                #pragma unroll
                for (int rf = 0; rf < 4; ++rf) {
                    int r = rf * 16 + l15;
                    af[rf] = *(const f16x8*)&hbuf[r * 512 + ((chb ^ (r & 7)) * 8)];
                }
                #pragma unroll
                for (int cf = 0; cf < 4; ++cf) {
                    int c = w * 64 + cf * 16 + l15;
                    f16x8 bf = *(const f16x8*)&btile[c * 64 + ((ch ^ (c & 7)) * 8)];
                    #pragma unroll
                    for (int rf = 0; rf < 4; ++rf)
                        acc2[rf][cf] = __builtin_amdgcn_mfma_f32_16x16x32_f16(af[rf], bf, acc2[rf][cf], 0, 0, 0);
                }
            }
        };

        #pragma unroll 1
        for (int s = 0; s < 8; s += 2) {
            step2(s,     cvA, cvB);
            step2(s + 1, cvB, cvA);
        }

        // ---- LayerNorm (+bias b1), residual, store ----
        float b1c[4], gc[4], bc[4];
        #pragma unroll
        for (int cf = 0; cf < 4; ++cf) {
            int c = w * 64 + cf * 16 + l15;
            b1c[cf] = b1[c]; gc[cf] = gma[c]; bc[cf] = bta[c];
        }
        #pragma unroll
        for (int rf = 0; rf < 4; ++rf)
            #pragma unroll
            for (int cf = 0; cf < 4; ++cf)
                #pragma unroll
                for (int i = 0; i < 4; ++i)
                    acc2[rf][cf][i] += b1c[cf];

        #pragma unroll
        for (int rf = 0; rf < 4; ++rf)
            #pragma unroll
            for (int i = 0; i < 4; ++i) {
                float p1 = 0.f, p2 = 0.f;
                #pragma unroll
                for (int cf = 0; cf < 4; ++cf) { float v = acc2[rf][cf][i]; p1 += v; p2 += v * v; }
                #pragma unroll
                for (int m = 1; m < 16; m <<= 1) { p1 += __shfl_xor(p1, m); p2 += __shfl_xor(p2, m); }
                if (l15 == 0) { int r = rf * 16 + lg * 4 + i; red1[r][w] = p1; red2[r][w] = p2; }
            }
        __syncthreads();
        if (tid < 64) {
            float s1 = 0.f, s2 = 0.f;
            #pragma unroll
            for (int ww = 0; ww < 8; ++ww) { s1 += red1[tid][ww]; s2 += red2[tid][ww]; }
            float mean = s1 * (1.f / 512.f);
            float var  = s2 * (1.f / 512.f) - mean * mean;
            mrow[tid] = mean;
            rrow[tid] = 1.f / sqrtf(var + 1e-5f);
        }
        __syncthreads();

        #pragma unroll
        for (int rf = 0; rf < 4; ++rf)
            #pragma unroll
            for (int i = 0; i < 4; ++i) {
                int r = rf * 16 + lg * 4 + i;
                float mean = mrow[r], rs = rrow[r];
                size_t grow = (size_t)(row0 + r);
                #pragma unroll
                for (int cf = 0; cf < 4; ++cf) {
                    int c = w * 64 + cf * 16 + l15;
                    float v = (acc2[rf][cf][i] - mean) * rs * gc[cf] + bc[cf];
                    if constexpr (MODE == 0) {
                        outF16[grow * 512 + c] = (f16)v;
                    } else if constexpr (MODE == 1) {
                        v += (float)eA[grow * 512 + c];          // residual += e
                        outF16[grow * 512 + c] = (f16)v;         // enew (aliases e: own rows only)
                    } else {
                        v += resF32[grow * 512 + c];             // residual += grid_nfeat
                        outF32[grow * 512 + c] = v;
                    }
                }
            }
    }
}

// ---------------------------------------------------------------- launch

extern "C" void kernel_launch(void* const* d_in, const int* in_sizes, int n_in,
                              void* d_out, int out_size, void* d_ws, size_t ws_size,
                              hipStream_t stream) {
    (void)in_sizes; (void)n_in; (void)out_size; (void)ws_size;

    const float* grid_nfeat = (const float*)d_in[0];
    const float* mesh_nfeat = (const float*)d_in[1];
    const int*   edge_index = (const int*)d_in[2];
    const float* efeat      = (const float*)d_in[3];
    const float* emb_W0 = (const float*)d_in[4];
    const float* emb_b0 = (const float*)d_in[5];
    const float* emb_W1 = (const float*)d_in[6];
    const float* emb_b1 = (const float*)d_in[7];
    const float* emb_g  = (const float*)d_in[8];
    const float* emb_b  = (const float*)d_in[9];
    const float* edge_W0 = (const float*)d_in[10];
    const float* edge_b0 = (const float*)d_in[11];
    const float* edge_W1 = (const float*)d_in[12];
    const float* edge_b1 = (const float*)d_in[13];
    const float* edge_g  = (const float*)d_in[14];
    const float* edge_bt = (const float*)d_in[15];
    const float* node_W0 = (const float*)d_in[16];
    const float* node_b0 = (const float*)d_in[17];
    const float* node_W1 = (const float*)d_in[18];
    const float* node_b1 = (const float*)d_in[19];
    const float* node_g  = (const float*)d_in[20];
    const float* node_bt = (const float*)d_in[21];

    const int* srcIdx = edge_index;
    const int* dstIdx = edge_index + NE;

    char* ws = (char*)d_ws;
    size_t off = 0;
    auto alloc = [&](size_t bytes) {
        void* p = ws + off;
        off += (bytes + 255) & ~(size_t)255;
        return p;
    };
    f16* grid_f16 = (f16*)alloc((size_t)NG * 512 * 2);
    f16* mesh_f16 = (f16*)alloc((size_t)NM * 512 * 2);
    f16* e_f16    = (f16*)alloc((size_t)NE * 512 * 2);   // also holds e_new in place
    f16* agg_f16  = (f16*)alloc((size_t)NG * 512 * 2);
    f16* w_emb1T  = (f16*)alloc((size_t)512 * 512 * 2);
    f16* w_edge0T = (f16*)alloc((size_t)512 * 1536 * 2);
    f16* w_edge1T = (f16*)alloc((size_t)512 * 512 * 2);
    f16* w_node0T = (f16*)alloc((size_t)512 * 1024 * 2);
    f16* w_node1T = (f16*)alloc((size_t)512 * 512 * 2);
    int* counts = (int*)alloc((size_t)NG * 4);
    int* offs   = (int*)alloc((size_t)(NG + 1) * 4);
    int* cursor = (int*)alloc((size_t)NG * 4);
    int* perm   = (int*)alloc((size_t)NE * 4);

    // --- prep ---
    hipMemsetAsync(counts, 0, (size_t)NG * 4, stream);
    cvt_rows_kernel<<<2048, 256, 0, stream>>>(grid_nfeat, grid_f16, NG * 512 / 4);
    cvt_rows_kernel<<<2048, 256, 0, stream>>>(mesh_nfeat, mesh_f16, NM * 512 / 4);
    transpose_w_kernel<<<512, 256, 0, stream>>>(emb_W1,  w_emb1T,  512);
    transpose_w_kernel<<<512, 256, 0, stream>>>(edge_W0, w_edge0T, 1536);
    transpose_w_kernel<<<512, 256, 0, stream>>>(edge_W1, w_edge1T, 512);
    transpose_w_kernel<<<512, 256, 0, stream>>>(node_W0, w_node0T, 1024);
    transpose_w_kernel<<<512, 256, 0, stream>>>(node_W1, w_node1T, 512);
    count_kernel<<<NE / 256, 256, 0, stream>>>(dstIdx, counts);
    scan_kernel<<<1, 1024, 0, stream>>>(counts, offs, cursor);
    fill_kernel<<<NE / 256, 256, 0, stream>>>(dstIdx, cursor, perm);

    // --- emb MLP: efeat -> e ---
    mlp_fused<0><<<NE / 64, 512, 0, stream>>>(
        efeat, nullptr, nullptr, nullptr, nullptr, nullptr,
        emb_W0, nullptr, emb_b0, w_emb1T, emb_b1, emb_g, emb_b,
        nullptr, nullptr, e_f16);

    // --- edge MLP: concat(e, mesh[src], grid[dst]) -> e_new (in place over e) ---
    mlp_fused<1><<<NE / 64, 512, 0, stream>>>(
        nullptr, e_f16, mesh_f16, grid_f16, srcIdx, dstIdx,
        nullptr, w_edge0T, edge_b0, w_edge1T, edge_b1, edge_g, edge_bt,
        nullptr, nullptr, e_f16);

    // --- scatter-sum: agg[node] = sum of e_new over incident edges ---
    agg_kernel<<<NG / 4, 256, 0, stream>>>(e_f16, offs, perm, agg_f16);

    // --- node MLP: concat(grid, agg) -> d_out ---
    mlp_fused<2><<<NG / 64, 512, 0, stream>>>(
        nullptr, nullptr, agg_f16, grid_f16, nullptr, nullptr,
        nullptr, w_node0T, node_b0, w_node1T, node_b1, node_g, node_bt,
        grid_nfeat, (float*)d_out, nullptr);
}

// Round 6
// 1762.547 us; speedup vs baseline: 1.0062x; 1.0062x over previous
//
#include <hip/hip_runtime.h>
#include <hip/hip_fp16.h>
#include <math.h>

// GraphCast mesh2grid decoder: emb MLP (perm-ordered out) -> edge MLP (CSR-ordered,
// sorted-dst gather, residual) -> streaming scatter-sum -> node MLP (+residual).
// All GEMMs f16 MFMA, fp32 accum.  K-loop staging is reg-pipelined DEPTH 2:
// slab s+2's global->reg loads issue right after slab s is flushed to LDS, so
// each load gets ~2 MFMA phases of latency cover and ds_writes wait on a
// counted vmcnt (compiler-tracked), not a drain.  MLP blocks are XCD-swizzled
// (T1): consecutive (dst-sorted) blocks share grid-row neighborhoods; chunked
// mapping keeps them on one XCD's L2.

#define NG 65536
#define NM 40962
#define NE 196608

using f16   = _Float16;
using f16x8 = __attribute__((ext_vector_type(8))) _Float16;
using f16x4 = __attribute__((ext_vector_type(4))) _Float16;
using f32x4 = __attribute__((ext_vector_type(4))) float;

// ---------------------------------------------------------------- prep kernels

__global__ void cvt_rows_kernel(const float* __restrict__ in, f16* __restrict__ out, int n4) {
    int stride = gridDim.x * blockDim.x;
    for (int i = blockIdx.x * blockDim.x + threadIdx.x; i < n4; i += stride) {
        float4 v = ((const float4*)in)[i];
        f16x4 o; o[0] = (f16)v.x; o[1] = (f16)v.y; o[2] = (f16)v.z; o[3] = (f16)v.w;
        ((f16x4*)out)[i] = o;
    }
}

// W [K][512] f32 -> WT [512][K] f16, LDS-tiled 64x64 (coalesced both sides)
__global__ void transpose_w_kernel(const float* __restrict__ W, f16* __restrict__ WT, int K) {
    __shared__ f16 t[64][66];
    const int nkb = K >> 6;
    const int kb = (blockIdx.x % nkb) << 6;
    const int cb = (blockIdx.x / nkb) << 6;
    const int tx = threadIdx.x & 63;
    const int ty = threadIdx.x >> 6;
    #pragma unroll
    for (int i = 0; i < 16; ++i) {
        int r = i * 4 + ty;
        t[r][tx] = (f16)W[(size_t)(kb + r) * 512 + (cb + tx)];
    }
    __syncthreads();
    #pragma unroll
    for (int i = 0; i < 16; ++i) {
        int c = i * 4 + ty;
        WT[(size_t)(cb + c) * K + (kb + tx)] = t[tx][c];
    }
}

// ---------------------------------------------------------------- CSR build

__global__ void count_kernel(const int* __restrict__ dst, int* __restrict__ counts) {
    int i = blockIdx.x * 256 + threadIdx.x;
    if (i < NE) atomicAdd(&counts[dst[i]], 1);
}

__global__ void scan_kernel(const int* __restrict__ counts, int* __restrict__ offs,
                            int* __restrict__ cursor) {
    __shared__ int part[1024];
    int t = threadIdx.x;
    int base = t * 64;
    int loc[64];
    int s = 0;
    #pragma unroll
    for (int i = 0; i < 64; ++i) { loc[i] = s; s += counts[base + i]; }
    part[t] = s;
    __syncthreads();
    for (int off = 1; off < 1024; off <<= 1) {
        int v = (t >= off) ? part[t - off] : 0;
        __syncthreads();
        part[t] += v;
        __syncthreads();
    }
    int pre = (t == 0) ? 0 : part[t - 1];
    #pragma unroll
    for (int i = 0; i < 64; ++i) { int o = pre + loc[i]; offs[base + i] = o; cursor[base + i] = o; }
    if (t == 1023) offs[65536] = pre + s;   // == NE
}

// perm[p] = original edge id; srcs/dsts[p] = its endpoints (dsts non-decreasing)
__global__ void fill_kernel(const int* __restrict__ src, const int* __restrict__ dst,
                            int* __restrict__ cursor, int* __restrict__ perm,
                            int* __restrict__ srcs, int* __restrict__ dsts) {
    int i = blockIdx.x * 256 + threadIdx.x;
    if (i < NE) {
        int d = dst[i];
        int p = atomicAdd(&cursor[d], 1);
        perm[p] = i;
        srcs[p] = src[i];
        dsts[p] = d;
    }
}

// ---------------------------------------------------------------- agg kernel
// agg[node] = sum of contiguous perm-ordered e_new rows [offs[n], offs[n+1]).
// Fully streaming reads; one wave per node, 4 waves/block, high occupancy.

__global__ void agg_kernel(const f16* __restrict__ enew,
                           const int* __restrict__ offs,
                           f16* __restrict__ agg) {
    int node = blockIdx.x * 4 + (threadIdx.x >> 6);
    int lane = threadIdx.x & 63;
    int beg = offs[node], end = offs[node + 1];
    float a[8] = {0.f, 0.f, 0.f, 0.f, 0.f, 0.f, 0.f, 0.f};
    for (int j = beg; j < end; ++j) {
        f16x8 v = *(const f16x8*)(enew + (size_t)j * 512 + lane * 8);
        #pragma unroll
        for (int i = 0; i < 8; ++i) a[i] += (float)v[i];
    }
    f16x8 o;
    #pragma unroll
    for (int i = 0; i < 8; ++i) o[i] = (f16)a[i];
    *(f16x8*)(agg + (size_t)node * 512 + lane * 8) = o;
}

// ---------------------------------------------------------------- fused MLP
// MODE 0: emb   x=[E,4] gathered via perm; out e_f16 in PERM ORDER
// MODE 1: edge  A=concat(e_perm, mesh[srcs], grid[dsts]) K1=1536; out enew_perm (+e resid)
// MODE 2: node  A=concat(grid, agg) (agg via meshA)      K1=1024; out d_out f32 (+grid resid)
//
// 64 rows/block, 512 threads (8 waves).  Wave w owns output cols [w*64, w*64+64).
// Stage1 -> SiLU -> h in LDS (f16, XOR-swizzled 16B chunks) -> Stage2 -> LN -> store.

template <int MODE>
__global__ __launch_bounds__(512, 2) __attribute__((flatten))
void mlp_fused(const float* __restrict__ xin,
               const f16*  eA,                      // aliases outF16 in MODE 1: no restrict
               const f16*  __restrict__ meshA,      // MODE 2: agg rows
               const f16*  __restrict__ gridA,
               const int*  __restrict__ srcIdx,     // MODE 1: perm-ordered srcs
               const int*  __restrict__ dstIdx,     // MODE 1: perm-ordered dsts (sorted)
               const int*  __restrict__ permIdx,    // MODE 0: perm
               const float* __restrict__ W0emb,
               const f16*  __restrict__ W0T,
               const float* __restrict__ b0,
               const f16*  __restrict__ W1T,
               const float* __restrict__ b1,
               const float* __restrict__ gma,
               const float* __restrict__ bta,
               const float* __restrict__ resF32,
               float* __restrict__ outF32,
               f16*  outF16)                        // aliases eA in MODE 1: no restrict
{
    constexpr int K1  = (MODE == 1) ? 1536 : (MODE == 2 ? 1024 : 64);
    constexpr int NS1 = (MODE == 0) ? 0 : K1 / 64;

    __shared__ __align__(16) f16 hbuf[64 * 512];    // h tile
    __shared__ __align__(16) f16 btile[512 * 64];   // B k-slab: [col][64k]
    __shared__ __align__(16) f16 atile[64 * 64];    // A k-slab: [row][64k]
    __shared__ float red1[64][8];
    __shared__ float red2[64][8];
    __shared__ float mrow[64];
    __shared__ float rrow[64];
    __shared__ float xemb[256];

    const int tid  = threadIdx.x;
    const int lane = tid & 63;
    const int w    = tid >> 6;
    const int l15  = lane & 15;
    const int lg   = lane >> 4;

    // T1 XCD-aware chunked swizzle (bijective: grid sizes are multiples of 8).
    // Consecutive dst-sorted blocks share grid-row neighborhoods -> same XCD L2.
    const int cpx  = (int)gridDim.x >> 3;
    const int bid  = ((int)blockIdx.x & 7) * cpx + ((int)blockIdx.x >> 3);
    const int row0 = bid * 64;

    // staging decomposition: each thread owns one 16B chunk per slab round
    const int ar   = tid >> 3;      // row/col-in-slab 0..63 (plus q*64 for B)
    const int ap   = tid & 7;       // chunk position 0..7
    const int aswz = ap ^ (ar & 7); // swizzled chunk slot

    int rid = 0, sid = 0, did = 0;
    if constexpr (MODE == 1 || MODE == 2) rid = row0 + ar;
    if constexpr (MODE == 1) { sid = srcIdx[rid]; did = dstIdx[rid]; }

    // B k-slab loader (stage-1 or stage-2 weights)
    auto ldB = [&](const f16* WT, int K, int s, f16x8 (&b_)[8]) {
        const int k0 = s * 64;
        #pragma unroll
        for (int q = 0; q < 8; ++q)
            b_[q] = *(const f16x8*)(WT + (size_t)(q * 64 + ar) * K + (k0 + ap * 8));
    };
    // A k-slab loader (stage-1 rows; sequential e/grid/agg, gathered mesh/grid[dst])
    auto ldA1 = [&](int s, f16x8& a_) {
        const int k0 = s * 64;
        if constexpr (MODE == 1) {
            const f16* p;
            if (k0 < 512)       p = eA    + (size_t)rid * 512 + (k0 + ap * 8);
            else if (k0 < 1024) p = meshA + (size_t)sid * 512 + (k0 - 512 + ap * 8);
            else                p = gridA + (size_t)did * 512 + (k0 - 1024 + ap * 8);
            a_ = *(const f16x8*)p;
        } else if constexpr (MODE == 2) {
            const f16* p = (k0 < 512)
                ? (gridA + (size_t)rid * 512 + (k0 + ap * 8))
                : (meshA + (size_t)rid * 512 + (k0 - 512 + ap * 8));   // agg rows
            a_ = *(const f16x8*)p;
        }
    };

    f16x8 cvA[8], cvB[8];                // stage-2 B pipeline regs (depth 2)
    if constexpr (MODE == 0) {           // emb: prefetch both stage-2 slabs at entry
        ldB(W1T, 512, 0, cvA);
        ldB(W1T, 512, 1, cvB);
    }

    f16x8 avA, avB, bvA[8], bvB[8];      // stage-1 pipeline regs (depth 2)
    if constexpr (MODE == 1 || MODE == 2) {
        ldA1(0, avA); ldB(W0T, K1, 0, bvA);
        ldA1(1, avB); ldB(W0T, K1, 1, bvB);
    }

    // ---- MODE 0 stage-1: [64,4] @ [4,512] + SiLU, fp32 direct (perm-gathered x) ----
    if constexpr (MODE == 0) {
        if (tid < 256) {
            int pr = permIdx[row0 + (tid >> 2)];
            xemb[tid] = xin[(size_t)pr * 4 + (tid & 3)];
        }
        __syncthreads();
        const int c = tid;
        float w0c0 = W0emb[c], w0c1 = W0emb[512 + c], w0c2 = W0emb[1024 + c], w0c3 = W0emb[1536 + c];
        float b0c = b0[c];
        const int cs = c >> 3, c7 = c & 7;
        #pragma unroll 4
        for (int r = 0; r < 64; ++r) {
            float v = b0c;
            v = fmaf(xemb[r * 4 + 0], w0c0, v);
            v = fmaf(xemb[r * 4 + 1], w0c1, v);
            v = fmaf(xemb[r * 4 + 2], w0c2, v);
            v = fmaf(xemb[r * 4 + 3], w0c3, v);
            v = v / (1.f + __expf(-v));                       // SiLU
            hbuf[r * 512 + ((cs ^ (r & 7)) * 8) + c7] = (f16)v;
        }
    }

    // ---- stage-1 MFMA GEMM (MODE 1/2): acc[64,512] = A[64,K1] @ W0T^T ----
    f32x4 acc2[4][4] = {};               // stage-2 accumulator
    if constexpr (MODE == 1 || MODE == 2) {
        f32x4 acc[4][4] = {};

        // flush slab s (in aC/bC) to LDS, then reuse aC/bC to issue slab s+2
        auto step1 = [&](int s, f16x8& aC, f16x8 (&bC)[8]) {
            __syncthreads();   // previous step's compute done reading slabs
            *(f16x8*)&atile[ar * 64 + aswz * 8] = aC;
            #pragma unroll
            for (int q = 0; q < 8; ++q)
                *(f16x8*)&btile[(q * 64 + ar) * 64 + aswz * 8] = bC[q];
            __syncthreads();

            if (s + 2 < NS1) { ldA1(s + 2, aC); ldB(W0T, K1, s + 2, bC); }

            #pragma unroll
            for (int ks = 0; ks < 2; ++ks) {
                const int ch = ks * 4 + lg;
                f16x8 af[4];
                #pragma unroll
                for (int rf = 0; rf < 4; ++rf) {
                    int r = rf * 16 + l15;
                    af[rf] = *(const f16x8*)&atile[r * 64 + ((ch ^ (r & 7)) * 8)];
                }
                #pragma unroll
                for (int cf = 0; cf < 4; ++cf) {
                    int c = w * 64 + cf * 16 + l15;
                    f16x8 bf = *(const f16x8*)&btile[c * 64 + ((ch ^ (c & 7)) * 8)];
                    #pragma unroll
                    for (int rf = 0; rf < 4; ++rf)
                        acc[rf][cf] = __builtin_amdgcn_mfma_f32_16x16x32_f16(af[rf], bf, acc[rf][cf], 0, 0, 0);
                }
            }
        };

        #pragma unroll 1
        for (int s = 0; s < NS1; s += 2) {
            step1(s,     avA, bvA);
            step1(s + 1, avB, bvB);
        }

        // prefetch stage-2 slabs 0,1 (fly during the h epilogue below)
        ldB(W1T, 512, 0, cvA);
        ldB(W1T, 512, 1, cvB);

        // h = silu(acc + b0) -> hbuf
        float b0c[4];
        #pragma unroll
        for (int cf = 0; cf < 4; ++cf) b0c[cf] = b0[w * 64 + cf * 16 + l15];
        #pragma unroll
        for (int rf = 0; rf < 4; ++rf)
            #pragma unroll
            for (int i = 0; i < 4; ++i) {
                int r = rf * 16 + lg * 4 + i;
                #pragma unroll
                for (int cf = 0; cf < 4; ++cf) {
                    int c = w * 64 + cf * 16 + l15;
                    float v = acc[rf][cf][i] + b0c[cf];
                    v = v / (1.f + __expf(-v));
                    hbuf[r * 512 + (((c >> 3) ^ (r & 7)) * 8) + (c & 7)] = (f16)v;
                }
            }
    }

    // ---- stage-2 MFMA GEMM: acc2[64,512] = h[64,512] @ W1T^T ----
    {
        auto step2 = [&](int s, f16x8 (&cC)[8]) {
            __syncthreads();   // h-writes visible / btile free
            #pragma unroll
            for (int q = 0; q < 8; ++q)
                *(f16x8*)&btile[(q * 64 + ar) * 64 + aswz * 8] = cC[q];
            __syncthreads();

            if (s + 2 < 8) ldB(W1T, 512, s + 2, cC);

            #pragma unroll
            for (int ks = 0; ks < 2; ++ks) {
                const int chb = s * 8 + ks * 4 + lg;
                const int ch  = ks * 4 + lg;
                f16x8 af[4];
                #pragma unroll
                for (int rf = 0; rf < 4; ++rf) {
                    int r = rf * 16 + l15;
                    af[rf] = *(const f16x8*)&hbuf[r * 512 + ((chb ^ (r & 7)) * 8)];
                }
                #pragma unroll
                for (int cf = 0; cf < 4; ++cf) {
                    int c = w * 64 + cf * 16 + l15;
                    f16x8 bf = *(const f16x8*)&btile[c * 64 + ((ch ^ (c & 7)) * 8)];
                    #pragma unroll
                    for (int rf = 0; rf < 4; ++rf)
                        acc2[rf][cf] = __builtin_amdgcn_mfma_f32_16x16x32_f16(af[rf], bf, acc2[rf][cf], 0, 0, 0);
                }
            }
        };

        #pragma unroll 1
        for (int s = 0; s < 8; s += 2) {
            step2(s,     cvA);
            step2(s + 1, cvB);
        }

        // ---- LayerNorm (+bias b1), residual, store ----
        float b1c[4], gc[4], bc[4];
        #pragma unroll
        for (int cf = 0; cf < 4; ++cf) {
            int c = w * 64 + cf * 16 + l15;
            b1c[cf] = b1[c]; gc[cf] = gma[c]; bc[cf] = bta[c];
        }
        #pragma unroll
        for (int rf = 0; rf < 4; ++rf)
            #pragma unroll
            for (int cf = 0; cf < 4; ++cf)
                #pragma unroll
                for (int i = 0; i < 4; ++i)
                    acc2[rf][cf][i] += b1c[cf];

        #pragma unroll
        for (int rf = 0; rf < 4; ++rf)
            #pragma unroll
            for (int i = 0; i < 4; ++i) {
                float p1 = 0.f, p2 = 0.f;
                #pragma unroll
                for (int cf = 0; cf < 4; ++cf) { float v = acc2[rf][cf][i]; p1 += v; p2 += v * v; }
                #pragma unroll
                for (int m = 1; m < 16; m <<= 1) { p1 += __shfl_xor(p1, m); p2 += __shfl_xor(p2, m); }
                if (l15 == 0) { int r = rf * 16 + lg * 4 + i; red1[r][w] = p1; red2[r][w] = p2; }
            }
        __syncthreads();
        if (tid < 64) {
            float s1 = 0.f, s2 = 0.f;
            #pragma unroll
            for (int ww = 0; ww < 8; ++ww) { s1 += red1[tid][ww]; s2 += red2[tid][ww]; }
            float mean = s1 * (1.f / 512.f);
            float var  = s2 * (1.f / 512.f) - mean * mean;
            mrow[tid] = mean;
            rrow[tid] = 1.f / sqrtf(var + 1e-5f);
        }
        __syncthreads();

        #pragma unroll
        for (int rf = 0; rf < 4; ++rf)
            #pragma unroll
            for (int i = 0; i < 4; ++i) {
                int r = rf * 16 + lg * 4 + i;
                float mean = mrow[r], rs = rrow[r];
                size_t grow = (size_t)(row0 + r);
                #pragma unroll
                for (int cf = 0; cf < 4; ++cf) {
                    int c = w * 64 + cf * 16 + l15;
                    float v = (acc2[rf][cf][i] - mean) * rs * gc[cf] + bc[cf];
                    if constexpr (MODE == 0) {
                        outF16[grow * 512 + c] = (f16)v;
                    } else if constexpr (MODE == 1) {
                        v += (float)eA[grow * 512 + c];          // residual += e
                        outF16[grow * 512 + c] = (f16)v;         // enew (aliases e: own rows only)
                    } else {
                        v += resF32[grow * 512 + c];             // residual += grid_nfeat
                        outF32[grow * 512 + c] = v;
                    }
                }
            }
    }
}

// ---------------------------------------------------------------- launch

extern "C" void kernel_launch(void* const* d_in, const int* in_sizes, int n_in,
                              void* d_out, int out_size, void* d_ws, size_t ws_size,
                              hipStream_t stream) {
    (void)in_sizes; (void)n_in; (void)out_size; (void)ws_size;

    const float* grid_nfeat = (const float*)d_in[0];
    const float* mesh_nfeat = (const float*)d_in[1];
    const int*   edge_index = (const int*)d_in[2];
    const float* efeat      = (const float*)d_in[3];
    const float* emb_W0 = (const float*)d_in[4];
    const float* emb_b0 = (const float*)d_in[5];
    const float* emb_W1 = (const float*)d_in[6];
    const float* emb_b1 = (const float*)d_in[7];
    const float* emb_g  = (const float*)d_in[8];
    const float* emb_b  = (const float*)d_in[9];
    const float* edge_W0 = (const float*)d_in[10];
    const float* edge_b0 = (const float*)d_in[11];
    const float* edge_W1 = (const float*)d_in[12];
    const float* edge_b1 = (const float*)d_in[13];
    const float* edge_g  = (const float*)d_in[14];
    const float* edge_bt = (const float*)d_in[15];
    const float* node_W0 = (const float*)d_in[16];
    const float* node_b0 = (const float*)d_in[17];
    const float* node_W1 = (const float*)d_in[18];
    const float* node_b1 = (const float*)d_in[19];
    const float* node_g  = (const float*)d_in[20];
    const float* node_bt = (const float*)d_in[21];

    const int* srcIdx = edge_index;
    const int* dstIdx = edge_index + NE;

    char* ws = (char*)d_ws;
    size_t off = 0;
    auto alloc = [&](size_t bytes) {
        void* p = ws + off;
        off += (bytes + 255) & ~(size_t)255;
        return p;
    };
    f16* grid_f16 = (f16*)alloc((size_t)NG * 512 * 2);
    f16* mesh_f16 = (f16*)alloc((size_t)NM * 512 * 2);
    f16* e_f16    = (f16*)alloc((size_t)NE * 512 * 2);   // perm-ordered; holds e_new in place
    f16* agg_f16  = (f16*)alloc((size_t)NG * 512 * 2);
    f16* w_emb1T  = (f16*)alloc((size_t)512 * 512 * 2);
    f16* w_edge0T = (f16*)alloc((size_t)512 * 1536 * 2);
    f16* w_edge1T = (f16*)alloc((size_t)512 * 512 * 2);
    f16* w_node0T = (f16*)alloc((size_t)512 * 1024 * 2);
    f16* w_node1T = (f16*)alloc((size_t)512 * 512 * 2);
    int* counts = (int*)alloc((size_t)NG * 4);
    int* offs   = (int*)alloc((size_t)(NG + 1) * 4);
    int* cursor = (int*)alloc((size_t)NG * 4);
    int* perm   = (int*)alloc((size_t)NE * 4);
    int* srcs   = (int*)alloc((size_t)NE * 4);
    int* dsts   = (int*)alloc((size_t)NE * 4);

    // --- prep ---
    hipMemsetAsync(counts, 0, (size_t)NG * 4, stream);
    cvt_rows_kernel<<<2048, 256, 0, stream>>>(grid_nfeat, grid_f16, NG * 512 / 4);
    cvt_rows_kernel<<<2048, 256, 0, stream>>>(mesh_nfeat, mesh_f16, NM * 512 / 4);
    transpose_w_kernel<<<(512 / 64) * 8,  256, 0, stream>>>(emb_W1,  w_emb1T,  512);
    transpose_w_kernel<<<(1536 / 64) * 8, 256, 0, stream>>>(edge_W0, w_edge0T, 1536);
    transpose_w_kernel<<<(512 / 64) * 8,  256, 0, stream>>>(edge_W1, w_edge1T, 512);
    transpose_w_kernel<<<(1024 / 64) * 8, 256, 0, stream>>>(node_W0, w_node0T, 1024);
    transpose_w_kernel<<<(512 / 64) * 8,  256, 0, stream>>>(node_W1, w_node1T, 512);
    count_kernel<<<NE / 256, 256, 0, stream>>>(dstIdx, counts);
    scan_kernel<<<1, 1024, 0, stream>>>(counts, offs, cursor);
    fill_kernel<<<NE / 256, 256, 0, stream>>>(srcIdx, dstIdx, cursor, perm, srcs, dsts);

    // --- emb MLP: efeat[perm] -> e (perm order) ---
    mlp_fused<0><<<NE / 64, 512, 0, stream>>>(
        efeat, nullptr, nullptr, nullptr, nullptr, nullptr, perm,
        emb_W0, nullptr, emb_b0, w_emb1T, emb_b1, emb_g, emb_b,
        nullptr, nullptr, e_f16);

    // --- edge MLP: concat(e, mesh[srcs], grid[dsts]) -> e_new (in place, perm order) ---
    mlp_fused<1><<<NE / 64, 512, 0, stream>>>(
        nullptr, e_f16, mesh_f16, grid_f16, srcs, dsts, nullptr,
        nullptr, w_edge0T, edge_b0, w_edge1T, edge_b1, edge_g, edge_bt,
        nullptr, nullptr, e_f16);

    // --- scatter-sum: agg[node] = streaming sum of contiguous e_new rows ---
    agg_kernel<<<NG / 4, 256, 0, stream>>>(e_f16, offs, agg_f16);

    // --- node MLP: concat(grid, agg) -> d_out ---
    mlp_fused<2><<<NG / 64, 512, 0, stream>>>(
        nullptr, nullptr, agg_f16, grid_f16, nullptr, nullptr, nullptr,
        nullptr, w_node0T, node_b0, w_node1T, node_b1, node_g, node_bt,
        grid_nfeat, (float*)d_out, nullptr);
}